// Round 1
// 6655.998 us; speedup vs baseline: 1.0556x; 1.0556x over previous
//
#include <hip/hip_runtime.h>
#include <math.h>

// TrAISformer forward, bf16-MFMA implementation (round 3).
// Round 3 change:
//  GEMM K-loop pipelined (T3+T4-lite): ring-of-3 LDS buffers, prefetch depth 2,
//  counted s_waitcnt vmcnt(8) instead of vmcnt(0) drain each K-step. Round-2
//  counters showed latency-bound GEMMs (MfmaUtil 19.5%, HBM 15%, Occ 16.6%):
//  the per-step vmcnt(0)+barrier exposed full L3/HBM staging latency with no
//  cross-block hiding. Now 8 global_load_lds stay in flight across barriers.
//  Second barrier after lgkmcnt(0) protects ring slot kt%3 from the next
//  iteration's stage(kt+3) write (write-after-read across waves).

#define LNUM 12
#define HNUM 12
#define DDIM 768
#define HDIM 64
#define TSEQ 256
#define NTOK 16384
#define DFF  3072
#define QKS  1536   // fused Q|K row stride
#define NOUTC 302   // real head width
#define NOUTP 384   // padded to 3x128 tiles

typedef unsigned short u16;
typedef __attribute__((ext_vector_type(8))) __bf16 bf16x8;
typedef __attribute__((ext_vector_type(8))) unsigned short u16x8;
typedef __attribute__((ext_vector_type(4))) float f32x4;

__device__ __forceinline__ u16 f2bf(float f) {
    union { float f; unsigned u; } v; v.f = f;
    return (u16)((v.u + 0x7fff + ((v.u >> 16) & 1)) >> 16);  // RNE
}

// async global->LDS, 16B per lane; LDS dest = wave-uniform base + lane*16
__device__ __forceinline__ void gl2lds16(const u16* g, u16* l) {
    __builtin_amdgcn_global_load_lds(
        (const __attribute__((address_space(1))) void*)g,
        (__attribute__((address_space(3))) void*)l, 16, 0, 0);
}

// ---------------- embedding: four-hot concat + pos ----------------
__global__ __launch_bounds__(256)
void embed_kernel(const int* __restrict__ idxs, const float* __restrict__ lat,
                  const float* __restrict__ lon, const float* __restrict__ sog,
                  const float* __restrict__ cog, const float* __restrict__ pos,
                  float* __restrict__ h) {
    int i = blockIdx.x * 256 + threadIdx.x;           // over NTOK*DDIM, exact
    int tok = i / DDIM, d = i - tok * DDIM;
    int t = tok & (TSEQ - 1);
    int tab = d / 192, sub = d - tab * 192;
    const float* tp = (tab == 0) ? lat : (tab == 1) ? lon : (tab == 2) ? sog : cog;
    int row = idxs[tok * 4 + tab];
    h[i] = tp[row * 192 + sub] + pos[t * DDIM + d];
}

// ---------------- LayerNorm: fp32 in -> bf16 out ----------------
__global__ __launch_bounds__(256)
void ln_kernel(const float* __restrict__ in, u16* __restrict__ out,
               const float* __restrict__ g, const float* __restrict__ b) {
    const int row = blockIdx.x, t = threadIdx.x;
    const float* x = in + (size_t)row * DDIM;
    float v0 = x[t], v1 = x[t + 256], v2 = x[t + 512];
    float s = v0 + v1 + v2;
    float sq = v0 * v0 + v1 * v1 + v2 * v2;
    #pragma unroll
    for (int m = 32; m; m >>= 1) { s += __shfl_xor(s, m); sq += __shfl_xor(sq, m); }
    __shared__ float red[8];
    const int w = t >> 6;
    if ((t & 63) == 0) { red[w] = s; red[4 + w] = sq; }
    __syncthreads();
    s  = red[0] + red[1] + red[2] + red[3];
    sq = red[4] + red[5] + red[6] + red[7];
    const float mean = s * (1.f / DDIM);
    const float rstd = rsqrtf(sq * (1.f / DDIM) - mean * mean + 1e-5f);
    u16* o = out + (size_t)row * DDIM;
    o[t]       = f2bf((v0 - mean) * rstd * g[t]       + b[t]);
    o[t + 256] = f2bf((v1 - mean) * rstd * g[t + 256] + b[t + 256]);
    o[t + 512] = f2bf((v2 - mean) * rstd * g[t + 512] + b[t + 512]);
}

// ------- weight convert+transpose: fp32 [R][C] -> bf16 [Cpad][R], pad rows zero -------
__global__ __launch_bounds__(256)
void wconv_kernel(const float* __restrict__ in, u16* __restrict__ out,
                  int R, int C, int Cpad) {
    __shared__ float tile[32][33];
    const float* src = in + (size_t)blockIdx.z * R * C;
    u16* dst = out + (size_t)blockIdx.z * (size_t)Cpad * R;
    const int c0 = blockIdx.x * 32, r0 = blockIdx.y * 32;
    const int tx = threadIdx.x & 31, ty = threadIdx.x >> 5;
    #pragma unroll
    for (int i = 0; i < 4; ++i) {
        int r = r0 + ty + i * 8, c = c0 + tx;                 // r<R guaranteed (R mult of 32)
        tile[ty + i * 8][tx] = (c < C) ? src[(size_t)r * C + c] : 0.f;
    }
    __syncthreads();
    #pragma unroll
    for (int i = 0; i < 4; ++i) {
        int oc = c0 + ty + i * 8;                             // < Cpad by grid
        dst[(size_t)oc * R + r0 + tx] = f2bf(tile[tx][ty + i * 8]);
    }
}

// ---------------- bf16 GEMM: C[M,N] = A[M,K] @ Bt[N,K]^T ----------------
// 128x128 tile, BK=32, 4 waves 2x2, mfma_f32_16x16x32_bf16, fp32 acc.
// Ring-of-3 LDS buffers, prefetch depth 2, counted vmcnt (T3/T4-lite).
// Grid: blockIdx.x = M-tile (fast), blockIdx.y = N-tile (slow) -> B L2-resident.
// MODE 0: bf16 out +bias | 1: bf16 gelu(acc+bias) | 2: f32 out +bias+res
//      3: f32 out, col<ncut, ld=ncut (head)
//      5: fused QKV: col<1536 -> bf16 qk[row*1536+col] (+bq/bk); else V^T scatter (+bv)
template <int MODE>
__global__ __launch_bounds__(256)
void gemm_bt(const u16* __restrict__ A, const u16* __restrict__ Bt,
             const float* __restrict__ bias, const float* __restrict__ bias2,
             const float* __restrict__ bias3, const float* __restrict__ res,
             void* __restrict__ Cout, int M, int N, int K, int ncut) {
    __shared__ u16 As[3][128][32] __attribute__((aligned(16)));
    __shared__ u16 Bs[3][128][32] __attribute__((aligned(16)));
    const int t = threadIdx.x;
    const int w = t >> 6, lane = t & 63;
    const int bm = blockIdx.x * 128, bn = blockIdx.y * 128;   // M fast, N slow
    const int moff = (w >> 1) * 64, noff = (w & 1) * 64;
    const int lrow = t >> 2, lcol = (t & 3) * 8;   // flat LDS byte offset == t*16
    const int fm = lane & 15, fq = lane >> 4;
    const f32x4 zero = {0.f, 0.f, 0.f, 0.f};
    f32x4 acc[4][4];
    #pragma unroll
    for (int a = 0; a < 4; ++a)
        #pragma unroll
        for (int c = 0; c < 4; ++c) acc[a][c] = zero;
    const u16* pA = A + (size_t)(bm + lrow) * K + lcol;
    const u16* pB = Bt + (size_t)(bn + lrow) * K + lcol;
    const size_t rstep = (size_t)64 * K;
    const int wr = w << 4;   // wave w stages rows wr..wr+15 and 64+wr..64+wr+15
    auto stage = [&](int s, int b) {
        const u16* ga = pA + s * 32;
        const u16* gb = pB + s * 32;
        gl2lds16(ga,         &As[b][wr][0]);
        gl2lds16(ga + rstep, &As[b][wr + 64][0]);
        gl2lds16(gb,         &Bs[b][wr][0]);
        gl2lds16(gb + rstep, &Bs[b][wr + 64][0]);
    };
    const int kts = K >> 5;                 // K-tiles (K mult of 32, >= 3 tiles)
    stage(0, 0);
    stage(1, 1);
    int bcur = 0, bpre = 2;                 // ring indices: compute buf / prefetch buf
    for (int kt = 0; kt < kts; ++kt) {
        if (kt + 2 < kts) stage(kt + 2, bpre);   // issue-early: 2 tiles in flight
        const int ahead = kts - 1 - kt;          // tiles staged beyond kt
        if (ahead >= 2)      asm volatile("s_waitcnt vmcnt(8)" ::: "memory");
        else if (ahead == 1) asm volatile("s_waitcnt vmcnt(4)" ::: "memory");
        else                 asm volatile("s_waitcnt vmcnt(0)" ::: "memory");
        __builtin_amdgcn_s_barrier();            // tile kt visible to all waves
        bf16x8 af[4], bfr[4];
        #pragma unroll
        for (int mt = 0; mt < 4; ++mt)
            af[mt] = __builtin_bit_cast(bf16x8, *(const u16x8*)&As[bcur][moff + mt * 16 + fm][fq * 8]);
        #pragma unroll
        for (int nt = 0; nt < 4; ++nt)
            bfr[nt] = __builtin_bit_cast(bf16x8, *(const u16x8*)&Bs[bcur][noff + nt * 16 + fm][fq * 8]);
        asm volatile("s_waitcnt lgkmcnt(0)" ::: "memory");
        __builtin_amdgcn_s_barrier();            // reads done: stage(kt+3) may clobber buf
        #pragma unroll
        for (int mt = 0; mt < 4; ++mt)
            #pragma unroll
            for (int nt = 0; nt < 4; ++nt)
                acc[mt][nt] = __builtin_amdgcn_mfma_f32_16x16x32_bf16(af[mt], bfr[nt], acc[mt][nt], 0, 0, 0);
        bcur = (bcur == 2) ? 0 : bcur + 1;
        bpre = (bpre == 2) ? 0 : bpre + 1;
    }
    #pragma unroll
    for (int mt = 0; mt < 4; ++mt) {
        #pragma unroll
        for (int nt = 0; nt < 4; ++nt) {
            const int col = bn + noff + nt * 16 + fm;
            float bv = 0.f;
            if (MODE == 5) {
                bv = (col < 768) ? bias[col] : (col < 1536) ? bias2[col - 768] : bias3[col - 1536];
            } else if (MODE != 3) {
                bv = bias[col];
            }
            #pragma unroll
            for (int i = 0; i < 4; ++i) {
                const int row = bm + moff + mt * 16 + fq * 4 + i;  // C/D: row=quad*4+reg, col=lane&15
                float v = acc[mt][nt][i] + bv;
                if (MODE == 0) {
                    ((u16*)Cout)[(size_t)row * N + col] = f2bf(v);
                } else if (MODE == 1) {
                    v = 0.5f * v * (1.f + erff(v * 0.70710678118654752f));  // exact gelu
                    ((u16*)Cout)[(size_t)row * N + col] = f2bf(v);
                } else if (MODE == 2) {
                    ((float*)Cout)[(size_t)row * N + col] = v + res[(size_t)row * N + col];
                } else if (MODE == 3) {
                    if (col < ncut) ((float*)Cout)[(size_t)row * ncut + col] = v;
                } else {  // MODE 5
                    if (col < 1536) {
                        ((u16*)Cout)[(size_t)row * QKS + col] = f2bf(v);
                    } else {           // V^T scatter -> Vt[(b*H+h)][d][t], Vt = Cout+ntok*1536
                        const int c = col - 1536;
                        const int bb = row >> 8, tt = row & 255;
                        const int hh = c >> 6, dd = c & 63;
                        u16* vt = (u16*)Cout + (size_t)NTOK * QKS;
                        vt[(((size_t)(bb * HNUM + hh)) * HDIM + dd) * TSEQ + tt] = f2bf(v);
                    }
                }
            }
        }
    }
}

// ---------------- fused causal attention ----------------
// grid (B*H, 4), block 256 = 4 waves; wave w -> query tile qt = by*4+w (16 rows).
// Q,K read from fused qk buffer (row stride 1536; K at col offset 768).
__global__ __launch_bounds__(256)
void attn_kernel(const u16* __restrict__ QK, const u16* __restrict__ Vt,
                 u16* __restrict__ Yb) {
    __shared__ u16 Pt[4][256][16] __attribute__((aligned(16)));  // [wave][kcol][qrow]
    const int bh = blockIdx.x;
    const int b = bh / HNUM, hh = bh - b * HNUM;
    const int w = threadIdx.x >> 6, lane = threadIdx.x & 63;
    const int fm = lane & 15, fq = lane >> 4;
    const int qt = blockIdx.y * 4 + w;
    const size_t qrow0 = (size_t)b * TSEQ;
    const int col0 = hh * HDIM;
    const u16* qp = QK + (qrow0 + qt * 16 + fm) * QKS + col0 + fq * 8;
    const bf16x8 aq0 = __builtin_bit_cast(bf16x8, *(const u16x8*)qp);        // k 0..31
    const bf16x8 aq1 = __builtin_bit_cast(bf16x8, *(const u16x8*)(qp + 32)); // k 32..63
    f32x4 s[16];
    #pragma unroll
    for (int kt = 0; kt < 16; ++kt) {
        if (kt <= qt) {                                   // causal tile skip (wave-uniform)
            const u16* kp = QK + (qrow0 + kt * 16 + fm) * QKS + 768 + col0 + fq * 8;
            bf16x8 bk0 = __builtin_bit_cast(bf16x8, *(const u16x8*)kp);
            bf16x8 bk1 = __builtin_bit_cast(bf16x8, *(const u16x8*)(kp + 32));
            f32x4 z = {0.f, 0.f, 0.f, 0.f};
            z = __builtin_amdgcn_mfma_f32_16x16x32_bf16(aq0, bk0, z, 0, 0, 0);
            z = __builtin_amdgcn_mfma_f32_16x16x32_bf16(aq1, bk1, z, 0, 0, 0);
            s[kt] = z;
        }
    }
    float lrow[4];
    #pragma unroll
    for (int i = 0; i < 4; ++i) {                         // row r = fq*4+i
        float mx = -1e30f;
        #pragma unroll
        for (int kt = 0; kt < 16; ++kt) {
            if (kt <= qt) {
                const bool valid = (kt < qt) || (fm <= fq * 4 + i);  // diag mask
                const float v = valid ? s[kt][i] * 0.125f : -1e30f;  // scale 1/sqrt(64)
                s[kt][i] = v;
                mx = fmaxf(mx, v);
            }
        }
        #pragma unroll
        for (int d = 1; d < 16; d <<= 1) mx = fmaxf(mx, __shfl_xor(mx, d));
        float sum = 0.f;
        #pragma unroll
        for (int kt = 0; kt < 16; ++kt) {
            if (kt <= qt) {
                const float e = __expf(s[kt][i] - mx);
                s[kt][i] = e;
                sum += e;
            }
        }
        #pragma unroll
        for (int d = 1; d < 16; d <<= 1) sum += __shfl_xor(sum, d);
        lrow[i] = sum;
    }
    const int nks = (qt + 2) >> 1;                        // 32-wide PV k-steps
    #pragma unroll
    for (int kt = 0; kt < 16; ++kt) {                     // P -> LDS transposed (8B stores)
        if (kt < 2 * nks) {
            unsigned lo = 0, hi = 0;
            if (kt <= qt) {
                lo = (unsigned)f2bf(s[kt][0]) | ((unsigned)f2bf(s[kt][1]) << 16);
                hi = (unsigned)f2bf(s[kt][2]) | ((unsigned)f2bf(s[kt][3]) << 16);
            }
            uint2 pk; pk.x = lo; pk.y = hi;
            *(uint2*)&Pt[w][kt * 16 + fm][fq * 4] = pk;
        }
    }
    __syncthreads();
    f32x4 o[4];
    #pragma unroll
    for (int dt = 0; dt < 4; ++dt) o[dt] = (f32x4){0.f, 0.f, 0.f, 0.f};
    #pragma unroll
    for (int ks = 0; ks < 8; ++ks) {
        if (ks < nks) {
            u16x8 praw;
            #pragma unroll
            for (int j = 0; j < 8; ++j) praw[j] = Pt[w][ks * 32 + fq * 8 + j][fm];  // A-frag
            const bf16x8 pa = __builtin_bit_cast(bf16x8, praw);
            #pragma unroll
            for (int dt = 0; dt < 4; ++dt) {
                const u16* vp = Vt + ((size_t)bh * HDIM + dt * 16 + fm) * TSEQ + ks * 32 + fq * 8;
                const bf16x8 bv = __builtin_bit_cast(bf16x8, *(const u16x8*)vp);
                o[dt] = __builtin_amdgcn_mfma_f32_16x16x32_bf16(pa, bv, o[dt], 0, 0, 0);
            }
        }
    }
    #pragma unroll
    for (int i = 0; i < 4; ++i) {
        const float inv = 1.f / lrow[i];
        #pragma unroll
        for (int dt = 0; dt < 4; ++dt)
            Yb[(qrow0 + qt * 16 + fq * 4 + i) * DDIM + col0 + dt * 16 + fm] = f2bf(o[dt][i] * inv);
    }
}

extern "C" void kernel_launch(void* const* d_in, const int* in_sizes, int n_in,
                              void* d_out, int out_size, void* d_ws, size_t ws_size,
                              hipStream_t stream) {
    (void)in_sizes; (void)n_in; (void)out_size; (void)ws_size;
    const int*   idxs  = (const int*)d_in[0];
    const float* lat   = (const float*)d_in[1];
    const float* lon   = (const float*)d_in[2];
    const float* sog   = (const float*)d_in[3];
    const float* cog   = (const float*)d_in[4];
    const float* pos   = (const float*)d_in[5];
    const float* ln1_g = (const float*)d_in[6];
    const float* ln1_b = (const float*)d_in[7];
    const float* ln2_g = (const float*)d_in[8];
    const float* ln2_b = (const float*)d_in[9];
    const float* Wq = (const float*)d_in[10];
    const float* bq = (const float*)d_in[11];
    const float* Wk = (const float*)d_in[12];
    const float* bk = (const float*)d_in[13];
    const float* Wv = (const float*)d_in[14];
    const float* bv = (const float*)d_in[15];
    const float* Wo = (const float*)d_in[16];
    const float* bo = (const float*)d_in[17];
    const float* W1 = (const float*)d_in[18];
    const float* b1 = (const float*)d_in[19];
    const float* W2 = (const float*)d_in[20];
    const float* b2 = (const float*)d_in[21];
    const float* lnf_g = (const float*)d_in[22];
    const float* lnf_b = (const float*)d_in[23];
    const float* Whead = (const float*)d_in[24];

    // workspace carve (~191 MB). ub overlays qk|vt|yb (NTOK*1536 + 2*NTOK*768 == NTOK*DFF bf16).
    char* base = (char*)d_ws;
    size_t off = 0;
    auto carve = [&](size_t bytes) { void* r = base + off; off += (bytes + 255) & ~(size_t)255; return r; };
    float* h  = (float*)carve((size_t)NTOK * DDIM * 4);
    u16* xb = (u16*)carve((size_t)NTOK * DDIM * 2);
    u16* qk = (u16*)carve((size_t)NTOK * QKS * 2);    // fused Q|K
    u16* vt = (u16*)carve((size_t)NTOK * DDIM * 2);   // V^T   (must follow qk: MODE5 offsets)
    u16* yb = (u16*)carve((size_t)NTOK * DDIM * 2);
    u16* ub = qk;  // contiguous overlay [NTOK][DFF]
    u16* WtQKV = (u16*)carve((size_t)3 * DDIM * DDIM * 2);  // concat rows: Q|K|V
    u16* WtO = (u16*)carve((size_t)DDIM * DDIM * 2);
    u16* Wt1 = (u16*)carve((size_t)DDIM * DFF * 2);
    u16* Wt2 = (u16*)carve((size_t)DFF * DDIM * 2);
    u16* WtH = (u16*)carve((size_t)NOUTP * DDIM * 2);

    embed_kernel<<<NTOK * DDIM / 256, 256, 0, stream>>>(idxs, lat, lon, sog, cog, pos, h);

    // grids: blockIdx.x = M-tile (fast), blockIdx.y = N-tile
    const dim3 g768(128, 6), g3072(128, 24), gqkv(128, 18), ghead(128, 3);
    const dim3 tq(24, 24, 1), t1(96, 24, 1), t2(24, 96, 1);
    const size_t wsq = (size_t)DDIM * DDIM, wsf = (size_t)DDIM * DFF;
    for (int l = 0; l < LNUM; ++l) {
        wconv_kernel<<<tq, 256, 0, stream>>>(Wq + l * wsq, WtQKV, DDIM, DDIM, DDIM);
        wconv_kernel<<<tq, 256, 0, stream>>>(Wk + l * wsq, WtQKV + wsq, DDIM, DDIM, DDIM);
        wconv_kernel<<<tq, 256, 0, stream>>>(Wv + l * wsq, WtQKV + 2 * wsq, DDIM, DDIM, DDIM);
        wconv_kernel<<<tq, 256, 0, stream>>>(Wo + l * wsq, WtO, DDIM, DDIM, DDIM);
        wconv_kernel<<<t1, 256, 0, stream>>>(W1 + l * wsf, Wt1, DDIM, DFF, DFF);
        wconv_kernel<<<t2, 256, 0, stream>>>(W2 + l * wsf, Wt2, DFF, DDIM, DDIM);

        ln_kernel<<<NTOK, 256, 0, stream>>>(h, xb, ln1_g + l * DDIM, ln1_b + l * DDIM);
        gemm_bt<5><<<gqkv, 256, 0, stream>>>(xb, WtQKV, bq + l * DDIM, bk + l * DDIM,
                                             bv + l * DDIM, nullptr, qk,
                                             NTOK, 3 * DDIM, DDIM, 0);
        attn_kernel<<<dim3(768, 4), 256, 0, stream>>>(qk, vt, yb);
        gemm_bt<2><<<g768, 256, 0, stream>>>(yb, WtO, bo + l * DDIM, nullptr, nullptr, h, h,
                                             NTOK, DDIM, DDIM, 0);
        ln_kernel<<<NTOK, 256, 0, stream>>>(h, xb, ln2_g + l * DDIM, ln2_b + l * DDIM);
        gemm_bt<1><<<g3072, 256, 0, stream>>>(xb, Wt1, b1 + l * DFF, nullptr, nullptr, nullptr, ub,
                                              NTOK, DFF, DDIM, 0);
        gemm_bt<2><<<g768, 256, 0, stream>>>(ub, Wt2, b2 + l * DDIM, nullptr, nullptr, h, h,
                                             NTOK, DDIM, DFF, 0);
    }
    ln_kernel<<<NTOK, 256, 0, stream>>>(h, xb, lnf_g, lnf_b);
    wconv_kernel<<<dim3(NOUTP / 32, DDIM / 32, 1), 256, 0, stream>>>(Whead, WtH, DDIM, NOUTC, NOUTP);
    gemm_bt<3><<<ghead, 256, 0, stream>>>(xb, WtH, nullptr, nullptr, nullptr, nullptr, d_out,
                                          NTOK, NOUTP, DDIM, NOUTC);
}